// Round 13
// baseline (101.122 us; speedup 1.0000x reference)
//
#include <hip/hip_runtime.h>
#include <stdint.h>

typedef unsigned short u16;
typedef __attribute__((ext_vector_type(8))) short short8;
typedef __attribute__((ext_vector_type(4))) float f32x4;

#define MFMA __builtin_amdgcn_mfma_f32_16x16x32_bf16

__device__ __forceinline__ u16 f2bf(float f) {
  union { float f; uint32_t u; } v; v.f = f;
  return (u16)((v.u + 0x7FFFu + ((v.u >> 16) & 1u)) >> 16);
}

#define GLOAD16(gp, lp) \
  __builtin_amdgcn_global_load_lds((const __attribute__((address_space(1))) uint32_t*)(gp), \
                                   (__attribute__((address_space(3))) uint32_t*)(lp), 16, 0, 0)

// ws layout (bytes)
#define WS_H    0          // u16 H[64][2][8][9][64][8]  fragment-major (9,437,184 B)
#define WS_Q1   9502720    // f32 q1[128]
#define WS_Q2   9503232    // f32 q2[128]
#define WS_M1P  9503744    // u64 m1p[64][4096]   (TRANSPOSED: [kt][row])
#define WS_M2P  11600896   // u64 m2p[64][4096]
#define WS_RS1  13698048   // f32 rs1[4096]
#define WS_RS2  13714432   // f32 rs2[4096]
#define WS_WSB  13730816   // u16 wsb[16][144][8] blocked B operand (36,864 B)

// ---------------- kernel 0: fused kmask (blocks 0-1023) + kprep (blocks 1024-1087) ----------------
__global__ __launch_bounds__(256) void k0(const int* __restrict__ sp,
                                          unsigned long long* __restrict__ m1p,
                                          unsigned long long* __restrict__ m2p,
                                          float* __restrict__ rs1, float* __restrict__ rs2,
                                          const float* __restrict__ W1, const float* __restrict__ Wb,
                                          const float* __restrict__ b1, const float* __restrict__ b2,
                                          const float* __restrict__ W2,
                                          float* __restrict__ q1, float* __restrict__ q2,
                                          u16* __restrict__ wsbg) {
  const int tid = threadIdx.x;
  if (blockIdx.x < 1024) {
    int wave = tid >> 6, lane = tid & 63;
    int i = blockIdx.x * 4 + wave;
    const int* rowp = sp + (size_t)i * 4096;
    int c1 = 0, c2 = 0;
    for (int w = 0; w < 64; ++w) {
      int v = rowp[w * 64 + lane];
      unsigned long long bb1 = __ballot(v <= 1);
      unsigned long long bb2 = __ballot(v == 2);
      if (lane == 0) {
        m1p[(size_t)w * 4096 + i] = bb1;
        m2p[(size_t)w * 4096 + i] = bb2;
        c1 += __popcll(bb1);
        c2 += __popcll(bb2);
      }
    }
    if (lane == 0) { rs1[i] = (float)c1; rs2[i] = (float)c2; }
    return;
  }
  int idx = (int)(blockIdx.x - 1024) * 256 + tid;   // 0..16383
  int a = idx >> 7, c = idx & 127;
  float acc = 0.f;
  for (int k = 0; k < 128; ++k) acc += W1[a * 128 + k] * Wb[k * 128 + c];
  wsbg[(((a >> 3) * 144) + c) * 8 + (a & 7)] = f2bf(acc);
  if (idx < 2048) {
    int k = idx >> 4, nn2 = idx & 15;
    wsbg[(((k >> 3) * 144) + 128 + nn2) * 8 + (k & 7)] = f2bf(W2[k * 16 + nn2]);
  }
  if (idx < 128) {
    float s1 = 0.f, s2 = 0.f;
    for (int k = 0; k < 128; ++k) s1 += b1[k] * Wb[k * 128 + idx];
    for (int k = 0; k < 16; ++k)  s2 += b2[k] * Wb[(128 + k) * 128 + idx];
    q1[idx] = s1; q2[idx] = s2;
  }
}

// ---------------- kernel A': u1h2 -> fragment-major H ----------------
// grid 512 (b = bid>>6, kt-slab = bid&63), 256 threads, 64 rows/block -> 2 blocks/CU.
__global__ __launch_bounds__(256, 2) void kproj(const float* __restrict__ x,
                                                const u16* __restrict__ wsbg,
                                                u16* __restrict__ H) {
  __shared__ u16 wsb[18432];              // blocked B operand (36 KB)
  __shared__ u16 xs[64 * 136];            // x rows bf16 (17.4 KB)
  __shared__ u16 hs[64 * 146];            // result staging (18.7 KB)
  const int tid = threadIdx.x;
  const int bid = blockIdx.x;
  const int b = bid >> 6;
  const int kt = bid & 63;
  const size_t r0 = (size_t)b * 4096 + (size_t)kt * 64;

  // stage blocked B via global_load_lds (36864 B)
#pragma unroll
  for (int i = 0; i < 9; ++i)
    GLOAD16(wsbg + (i * 256 + tid) * 8, (char*)&wsb[0] + (i * 256 + tid) * 16);
  // stage x rows -> xs[64][136] bf16
  {
    const float* xp = x + (r0 + (tid >> 2)) * 128 + (tid & 3) * 32;
    u16* xd = xs + (tid >> 2) * 136 + (tid & 3) * 32;
#pragma unroll
    for (int i = 0; i < 4; ++i) {
      f32x4 a = ((const f32x4*)xp)[i * 2];
      f32x4 bq = ((const f32x4*)xp)[i * 2 + 1];
      short8 pk;
      pk[0] = (short)f2bf(a[0]); pk[1] = (short)f2bf(a[1]);
      pk[2] = (short)f2bf(a[2]); pk[3] = (short)f2bf(a[3]);
      pk[4] = (short)f2bf(bq[0]); pk[5] = (short)f2bf(bq[1]);
      pk[6] = (short)f2bf(bq[2]); pk[7] = (short)f2bf(bq[3]);
      *(short8*)(xd + i * 8) = pk;
    }
  }
  __syncthreads();

  const int w = tid >> 6, l = tid & 63, lr = l & 15, lg = l >> 4;
  f32x4 acc[9];
  f32x4 zz = {0.f, 0.f, 0.f, 0.f};
#pragma unroll
  for (int fn = 0; fn < 9; ++fn) acc[fn] = zz;
#pragma unroll
  for (int kf = 0; kf < 4; ++kf) {
    short8 af = *(const short8*)(xs + (w * 16 + lr) * 136 + kf * 32 + lg * 8);
#pragma unroll
    for (int fn = 0; fn < 9; ++fn) {
      short8 bf = *(const short8*)(wsb + (((kf * 4 + lg) * 144) + fn * 16 + lr) * 8);
      acc[fn] = MFMA(af, bf, acc[fn], 0, 0, 0);
    }
  }
  __syncthreads();
#pragma unroll
  for (int fn = 0; fn < 9; ++fn)
#pragma unroll
    for (int g = 0; g < 4; ++g)
      hs[(w * 16 + lg * 4 + g) * 146 + fn * 16 + lr] = f2bf(acc[fn][g]);
  __syncthreads();
  // fragment-major coalesced write to H (1 kt-slab = 1152 x 16B chunks)
  for (int i = 0; i < 5; ++i) {
    int e = i * 256 + tid;
    if (e < 1152) {
      int jbl = e / 144, n = e % 144;
      union { u16 s[8]; uint4 v; } pk;
#pragma unroll
      for (int r = 0; r < 8; ++r) pk.s[r] = hs[(jbl * 8 + r) * 146 + n];
      int kf = jbl >> 2, lgw = jbl & 3, fn = n >> 4, lrw = n & 15;
      size_t di = ((((size_t)kt * 2 + kf) * 8 + b) * 9 + fn) * 512 + (lgw * 16 + lrw) * 8;
      *(uint4*)(H + di) = pk.v;
    }
  }
}

// expand 8 mask bits (byte lgsh/8 of a 32-bit half-word) -> 8 bf16 {0,1} packed as short8
__device__ __forceinline__ short8 expand_byte(uint32_t wd, int lgsh) {
  uint32_t b = (wd >> lgsh) & 0xFFu;
  uint32_t t = b * 0x8001u;
  union { uint32_t u[4]; short8 s; } r;
  r.u[0] = (t & 0x00010001u) * 0x3F80u;
  r.u[1] = (t & 0x00040004u) * 0x0FE0u;
  r.u[2] = (t & 0x00100010u) * 0x03F8u;
  r.u[3] = (t & 0x00400040u) * 0x00FEu;
  return r.s;
}

// ---------------- kernel B1: K=128 phases (2 kt/barrier), masks in registers ----------------
// grid 256 (b=bid&7 XCD-pinned, 128-row panels), 1024 thr = 16 waves (4g x 4c).
// Per phase: [wait vmcnt(S); barrier; maskload(p+1) (6 loads, BEFORE stage); stage(p+2) (S loads);
// compute(p) = 2 kt x 9 MFMA]. FIFO vmcnt(S) drains masks+old stage, keeps newest stage in flight.
__global__ __launch_bounds__(1024, 4) void kb1(const u16* __restrict__ H,
                                               const uint2* __restrict__ M1,
                                               const uint32_t* __restrict__ M2w,
                                               const float* __restrict__ rs1, const float* __restrict__ rs2,
                                               const float* __restrict__ q1, const float* __restrict__ q2,
                                               const float* __restrict__ Wb, const float* __restrict__ bb,
                                               float* __restrict__ out) {
  __shared__ u16 bt[3][18432];             // 3 x 2-slab buffers (110.6 KB)
  __shared__ float f2pf[2][128][16];       // m2@h2 kf-partials (16 KB)
  __shared__ u16 f2s[128 * 40];            // f2 bf16, K padded to 32 (10 KB)
  __shared__ u16 wb2s[4096];               // Wb2 padded to K=32 (8 KB)  -> 144.6 KB

  const int tid = threadIdx.x;
  const int bid = blockIdx.x;
  const int b = bid & 7;
  const int i0 = (bid >> 3) * 128;

  const int w = tid >> 6, l = tid & 63, lr = l & 15, lg = l >> 4;
  const int g = w >> 2, c = w & 3;
  const int fm2 = w & 7, kf2 = w >> 3;
  const int lgsh = lg * 8;

  // stage Wb2 FIRST (its loads + compiler waits fully retire before pipeline starts)
#pragma unroll
  for (int i = 0; i < 4; ++i) {
    int e = i * 1024 + tid;
    int r_ = e & 7, nn = (e >> 3) & 127, jb = e >> 10;
    int k = jb * 8 + r_;
    wb2s[e] = f2bf((k < 16) ? Wb[(128 + k) * 128 + nn] : 0.f);
  }

  // stage chunks: ch0 = tid, ch1 = 1024+tid, ch2 = 2048+tid (tid<256 only)
  auto choff = [&](int ch) -> uint32_t {
    int slab = (ch >= 1152) ? 1 : 0;
    int r = ch - slab * 1152;
    return (uint32_t)(slab * 73728 + (r < 576 ? b * 4608 + r * 8 : 36864 + b * 4608 + (r - 576) * 8));
  };
  const u16* pB0 = H + choff(tid);
  const u16* pB1 = H + choff(1024 + tid);
  const u16* pB2 = H + choff(tid < 256 ? 2048 + tid : 2048);
  const int dB0 = tid * 16, dB1 = (1024 + tid) * 16, dB2 = (2048 + tid) * 16;

#define STAGE(BUF) { \
    GLOAD16(pB0, (char*)&bt[BUF][0] + dB0); \
    GLOAD16(pB1, (char*)&bt[BUF][0] + dB1); \
    if (tid < 256) GLOAD16(pB2, (char*)&bt[BUF][0] + dB2); \
    pB0 += 147456; pB1 += 147456; pB2 += 147456; }

  // mask pointers (transposed layout M[kt*4096 + row]); loaded to registers 1 phase ahead
  const uint2* mp1a = M1 + i0 + (g * 2 + 0) * 16 + lr;
  const uint2* mp1b = M1 + i0 + (g * 2 + 1) * 16 + lr;
  const uint32_t* mp2 = M2w + (size_t)(i0 + fm2 * 16 + lr) * 2 + kf2;
  size_t mo1 = 0, mo2 = 0;

  uint2 PA0, PB0, PA1, PB1, QA0, QB0, QA1, QB1, RA0, RB0, RA1, RB1;
  uint32_t PC0, PC1, QC0, QC1, RC0, RC1;

#define MLOAD(S) { \
    S##A0 = mp1a[mo1]; S##B0 = mp1b[mo1]; S##C0 = mp2[mo2]; \
    S##A1 = mp1a[mo1 + 4096]; S##B1 = mp1b[mo1 + 4096]; S##C1 = mp2[mo2 + 8192]; \
    mo1 += 8192; mo2 += 16384; }

  // compute-phase LDS fragment offsets (u16, within one slab)
  const int fA0 = (c * 2 + 0) * 512 + l * 8;
  const int fA1 = (c * 2 + 1) * 512 + l * 8;
  const int fB0 = 4608 + fA0;
  const int fB1 = 4608 + fA1;
  const int fM  = kf2 * 4608 + 4096 + l * 8;

  f32x4 zz = {0.f, 0.f, 0.f, 0.f};
  f32x4 acc00 = zz, acc01 = zz, acc10 = zz, acc11 = zz;
  f32x4 acc2 = zz;

#define WAITV { if (w < 4) asm volatile("s_waitcnt vmcnt(3)" ::: "memory"); \
                else asm volatile("s_waitcnt vmcnt(2)" ::: "memory"); }

#define CKT(BUF, S, MA, MB, MC) { \
    const u16* src_ = &bt[BUF][(S) * 9216]; \
    short8 bA0_ = *(const short8*)(src_ + fA0); \
    short8 bA1_ = *(const short8*)(src_ + fA1); \
    short8 bB0_ = *(const short8*)(src_ + fB0); \
    short8 bB1_ = *(const short8*)(src_ + fB1); \
    short8 bM_  = *(const short8*)(src_ + fM); \
    short8 e0x_ = expand_byte(MA.x, lgsh), e0y_ = expand_byte(MA.y, lgsh); \
    short8 e1x_ = expand_byte(MB.x, lgsh), e1y_ = expand_byte(MB.y, lgsh); \
    short8 e2v_ = expand_byte(MC, lgsh); \
    __builtin_amdgcn_s_setprio(1); \
    acc00 = MFMA(e0x_, bA0_, acc00, 0, 0, 0); \
    acc01 = MFMA(e0x_, bA1_, acc01, 0, 0, 0); \
    acc00 = MFMA(e0y_, bB0_, acc00, 0, 0, 0); \
    acc01 = MFMA(e0y_, bB1_, acc01, 0, 0, 0); \
    acc10 = MFMA(e1x_, bA0_, acc10, 0, 0, 0); \
    acc11 = MFMA(e1x_, bA1_, acc11, 0, 0, 0); \
    acc10 = MFMA(e1y_, bB0_, acc10, 0, 0, 0); \
    acc11 = MFMA(e1y_, bB1_, acc11, 0, 0, 0); \
    acc2  = MFMA(e2v_, bM_, acc2, 0, 0, 0); \
    __builtin_amdgcn_s_setprio(0); }

#define COMPUTE2(BUF, S) { CKT(BUF, 0, S##A0, S##B0, S##C0) CKT(BUF, 1, S##A1, S##B1, S##C1) }

  // prologue: masks(phase0) -> P; stage phase0 -> buf0, phase1 -> buf1
  MLOAD(P);
  STAGE(0);
  STAGE(1);

  for (int it = 0; it < 10; ++it) {        // phases 0..29
    WAITV; __builtin_amdgcn_s_barrier(); MLOAD(Q); STAGE(2); COMPUTE2(0, P);
    WAITV; __builtin_amdgcn_s_barrier(); MLOAD(R); STAGE(0); COMPUTE2(1, Q);
    WAITV; __builtin_amdgcn_s_barrier(); MLOAD(P); STAGE(1); COMPUTE2(2, R);
  }
  // phase 30 (buf0, masks P): load masks(31) -> Q, no stage
  WAITV; __builtin_amdgcn_s_barrier(); MLOAD(Q); COMPUTE2(0, P);
  // phase 31 (buf1, masks Q)
  asm volatile("s_waitcnt vmcnt(0)" ::: "memory");
  __builtin_amdgcn_s_barrier(); COMPUTE2(1, Q);

  // epilogue: combine m2 kf-partials -> f2 bf16 tile
#pragma unroll
  for (int gg = 0; gg < 4; ++gg)
    f2pf[kf2][fm2 * 16 + lg * 4 + gg][lr] = acc2[gg];
  __syncthreads();
#pragma unroll
  for (int j = 0; j < 2; ++j) {
    int e = j * 1024 + tid;                // 128x16 = 2048 elems
    int row = e >> 4, col = e & 15;
    f2s[row * 40 + col] = f2bf(f2pf[0][row][col] + f2pf[1][row][col]);
    f2s[row * 40 + 16 + col] = 0;
  }
  __syncthreads();

  // epilogue MFMA: acc[i][fj] += f2frag(fm=2g+i) x Wb2frag(fn=2c+fj)
  short8 bw0 = *(const short8*)(wb2s + ((lg * 128) + (c * 2 + 0) * 16 + lr) * 8);
  short8 bw1 = *(const short8*)(wb2s + ((lg * 128) + (c * 2 + 1) * 16 + lr) * 8);
  {
    short8 af0 = *(const short8*)(f2s + ((g * 2 + 0) * 16 + lr) * 40 + lg * 8);
    short8 af1 = *(const short8*)(f2s + ((g * 2 + 1) * 16 + lr) * 40 + lg * 8);
    acc00 = MFMA(af0, bw0, acc00, 0, 0, 0);
    acc01 = MFMA(af0, bw1, acc01, 0, 0, 0);
    acc10 = MFMA(af1, bw0, acc10, 0, 0, 0);
    acc11 = MFMA(af1, bw1, acc11, 0, 0, 0);
  }

  // final: + rs1*q1 + rs2*q2 + bb, store f32
  const int col0 = (c * 2 + 0) * 16 + lr, col1 = (c * 2 + 1) * 16 + lr;
  const float q10 = q1[col0], q20 = q2[col0], bb0 = bb[col0];
  const float q11 = q1[col1], q21 = q2[col1], bb1 = bb[col1];
#pragma unroll
  for (int i = 0; i < 2; ++i) {
    f32x4 a0 = i ? acc10 : acc00;
    f32x4 a1 = i ? acc11 : acc01;
#pragma unroll
    for (int gg = 0; gg < 4; ++gg) {
      int row = (g * 2 + i) * 16 + lg * 4 + gg;
      float r1 = rs1[i0 + row], r2 = rs2[i0 + row];
      size_t obase = ((size_t)b * 4096 + i0 + row) * 128;
      out[obase + col0] = a0[gg] + r1 * q10 + r2 * q20 + bb0;
      out[obase + col1] = a1[gg] + r1 * q11 + r2 * q21 + bb1;
    }
  }
}

extern "C" void kernel_launch(void* const* d_in, const int* in_sizes, int n_in,
                              void* d_out, int out_size, void* d_ws, size_t ws_size,
                              hipStream_t stream) {
  const float* x  = (const float*)d_in[0];
  const int*   sp = (const int*)d_in[1];
  const float* W1 = (const float*)d_in[2];
  const float* b1 = (const float*)d_in[3];
  const float* W2 = (const float*)d_in[4];
  const float* b2 = (const float*)d_in[5];
  const float* Wb = (const float*)d_in[6];
  const float* bb = (const float*)d_in[7];
  float* out = (float*)d_out;
  char* ws = (char*)d_ws;

  u16* H = (u16*)(ws + WS_H);
  float* q1 = (float*)(ws + WS_Q1);
  float* q2 = (float*)(ws + WS_Q2);
  unsigned long long* m1p = (unsigned long long*)(ws + WS_M1P);
  unsigned long long* m2p = (unsigned long long*)(ws + WS_M2P);
  float* rs1 = (float*)(ws + WS_RS1);
  float* rs2 = (float*)(ws + WS_RS2);
  u16* wsbg = (u16*)(ws + WS_WSB);

  k0<<<1088, 256, 0, stream>>>(sp, m1p, m2p, rs1, rs2, W1, Wb, b1, b2, W2, q1, q2, wsbg);
  kproj<<<512, 256, 0, stream>>>(x, wsbg, H);
  kb1<<<256, 1024, 0, stream>>>(H, (const uint2*)m1p, (const uint32_t*)m2p,
                                rs1, rs2, q1, q2, Wb, bb, out);
}

// Round 14
// 91.987 us; speedup vs baseline: 1.0993x; 1.0993x over previous
//
#include <hip/hip_runtime.h>
#include <stdint.h>

typedef unsigned short u16;
typedef __attribute__((ext_vector_type(8))) short short8;
typedef __attribute__((ext_vector_type(4))) float f32x4;

#define MFMA __builtin_amdgcn_mfma_f32_16x16x32_bf16

__device__ __forceinline__ u16 f2bf(float f) {
  union { float f; uint32_t u; } v; v.f = f;
  return (u16)((v.u + 0x7FFFu + ((v.u >> 16) & 1u)) >> 16);
}

#define GLOAD16(gp, lp) \
  __builtin_amdgcn_global_load_lds((const __attribute__((address_space(1))) uint32_t*)(gp), \
                                   (__attribute__((address_space(3))) uint32_t*)(lp), 16, 0, 0)

// ws layout (bytes)
#define WS_H    0          // u16 H[64][2][8][9][64][8]  fragment-major (9,437,184 B)
#define WS_Q1   9502720    // f32 q1[128]
#define WS_Q2   9503232    // f32 q2[128]
#define WS_M1P  9503744    // u64 m1p[64][4096]   (TRANSPOSED: [kt][row])
#define WS_M2P  11600896   // u64 m2p[64][4096]
#define WS_RS1  13698048   // f32 rs1[4096]
#define WS_RS2  13714432   // f32 rs2[4096]
#define WS_WSB  13730816   // u16 wsb[16][144][8] blocked B operand (36,864 B)

// ---------------- kernel 0: fused kmask (blocks 0-1023) + kprep (blocks 1024-1087) ----------------
__global__ __launch_bounds__(256) void k0(const int* __restrict__ sp,
                                          unsigned long long* __restrict__ m1p,
                                          unsigned long long* __restrict__ m2p,
                                          float* __restrict__ rs1, float* __restrict__ rs2,
                                          const float* __restrict__ W1, const float* __restrict__ Wb,
                                          const float* __restrict__ b1, const float* __restrict__ b2,
                                          const float* __restrict__ W2,
                                          float* __restrict__ q1, float* __restrict__ q2,
                                          u16* __restrict__ wsbg) {
  const int tid = threadIdx.x;
  if (blockIdx.x < 1024) {
    int wave = tid >> 6, lane = tid & 63;
    int i = blockIdx.x * 4 + wave;
    const int* rowp = sp + (size_t)i * 4096;
    int c1 = 0, c2 = 0;
    for (int w = 0; w < 64; ++w) {
      int v = rowp[w * 64 + lane];
      unsigned long long bb1 = __ballot(v <= 1);
      unsigned long long bb2 = __ballot(v == 2);
      if (lane == 0) {
        m1p[(size_t)w * 4096 + i] = bb1;
        m2p[(size_t)w * 4096 + i] = bb2;
        c1 += __popcll(bb1);
        c2 += __popcll(bb2);
      }
    }
    if (lane == 0) { rs1[i] = (float)c1; rs2[i] = (float)c2; }
    return;
  }
  int idx = (int)(blockIdx.x - 1024) * 256 + tid;   // 0..16383
  int a = idx >> 7, c = idx & 127;
  float acc = 0.f;
  for (int k = 0; k < 128; ++k) acc += W1[a * 128 + k] * Wb[k * 128 + c];
  wsbg[(((a >> 3) * 144) + c) * 8 + (a & 7)] = f2bf(acc);
  if (idx < 2048) {
    int k = idx >> 4, nn2 = idx & 15;
    wsbg[(((k >> 3) * 144) + 128 + nn2) * 8 + (k & 7)] = f2bf(W2[k * 16 + nn2]);
  }
  if (idx < 128) {
    float s1 = 0.f, s2 = 0.f;
    for (int k = 0; k < 128; ++k) s1 += b1[k] * Wb[k * 128 + idx];
    for (int k = 0; k < 16; ++k)  s2 += b2[k] * Wb[(128 + k) * 128 + idx];
    q1[idx] = s1; q2[idx] = s2;
  }
}

// ---------------- kernel A': u1h2 -> fragment-major H ----------------
// grid 512 (b = bid>>6, kt-slab = bid&63), 256 threads, 64 rows/block -> 2 blocks/CU.
__global__ __launch_bounds__(256, 2) void kproj(const float* __restrict__ x,
                                                const u16* __restrict__ wsbg,
                                                u16* __restrict__ H) {
  __shared__ u16 wsb[18432];              // blocked B operand (36 KB)
  __shared__ u16 xs[64 * 136];            // x rows bf16 (17.4 KB)
  __shared__ u16 hs[64 * 146];            // result staging (18.7 KB)
  const int tid = threadIdx.x;
  const int bid = blockIdx.x;
  const int b = bid >> 6;
  const int kt = bid & 63;
  const size_t r0 = (size_t)b * 4096 + (size_t)kt * 64;

#pragma unroll
  for (int i = 0; i < 9; ++i)
    GLOAD16(wsbg + (i * 256 + tid) * 8, (char*)&wsb[0] + (i * 256 + tid) * 16);
  {
    const float* xp = x + (r0 + (tid >> 2)) * 128 + (tid & 3) * 32;
    u16* xd = xs + (tid >> 2) * 136 + (tid & 3) * 32;
#pragma unroll
    for (int i = 0; i < 4; ++i) {
      f32x4 a = ((const f32x4*)xp)[i * 2];
      f32x4 bq = ((const f32x4*)xp)[i * 2 + 1];
      short8 pk;
      pk[0] = (short)f2bf(a[0]); pk[1] = (short)f2bf(a[1]);
      pk[2] = (short)f2bf(a[2]); pk[3] = (short)f2bf(a[3]);
      pk[4] = (short)f2bf(bq[0]); pk[5] = (short)f2bf(bq[1]);
      pk[6] = (short)f2bf(bq[2]); pk[7] = (short)f2bf(bq[3]);
      *(short8*)(xd + i * 8) = pk;
    }
  }
  __syncthreads();

  const int w = tid >> 6, l = tid & 63, lr = l & 15, lg = l >> 4;
  f32x4 acc[9];
  f32x4 zz = {0.f, 0.f, 0.f, 0.f};
#pragma unroll
  for (int fn = 0; fn < 9; ++fn) acc[fn] = zz;
#pragma unroll
  for (int kf = 0; kf < 4; ++kf) {
    short8 af = *(const short8*)(xs + (w * 16 + lr) * 136 + kf * 32 + lg * 8);
#pragma unroll
    for (int fn = 0; fn < 9; ++fn) {
      short8 bf = *(const short8*)(wsb + (((kf * 4 + lg) * 144) + fn * 16 + lr) * 8);
      acc[fn] = MFMA(af, bf, acc[fn], 0, 0, 0);
    }
  }
  __syncthreads();
#pragma unroll
  for (int fn = 0; fn < 9; ++fn)
#pragma unroll
    for (int g = 0; g < 4; ++g)
      hs[(w * 16 + lg * 4 + g) * 146 + fn * 16 + lr] = f2bf(acc[fn][g]);
  __syncthreads();
  for (int i = 0; i < 5; ++i) {
    int e = i * 256 + tid;
    if (e < 1152) {
      int jbl = e / 144, n = e % 144;
      union { u16 s[8]; uint4 v; } pk;
#pragma unroll
      for (int r = 0; r < 8; ++r) pk.s[r] = hs[(jbl * 8 + r) * 146 + n];
      int kf = jbl >> 2, lgw = jbl & 3, fn = n >> 4, lrw = n & 15;
      size_t di = ((((size_t)kt * 2 + kf) * 8 + b) * 9 + fn) * 512 + (lgw * 16 + lrw) * 8;
      *(uint4*)(H + di) = pk.v;
    }
  }
}

// expand 8 mask bits (byte lgsh/8 of a 32-bit half-word) -> 8 bf16 {0,1} packed as short8
__device__ __forceinline__ short8 expand_byte(uint32_t wd, int lgsh) {
  uint32_t b = (wd >> lgsh) & 0xFFu;
  uint32_t t = b * 0x8001u;
  union { uint32_t u[4]; short8 s; } r;
  r.u[0] = (t & 0x00010001u) * 0x3F80u;
  r.u[1] = (t & 0x00040004u) * 0x0FE0u;
  r.u[2] = (t & 0x00100010u) * 0x03F8u;
  r.u[3] = (t & 0x00400040u) * 0x00FEu;
  return r.s;
}

// ---------------- kernel B1: 2-kt phases (32 barriers), masks via LDS DMA (R12-proven path) ----------------
// grid 256 (b=bid&7 XCD-pinned, 128-row panels), 1024 thr = 16 waves (4g x 4c).
// Per phase: [wait vmcnt(L); barrier; stage(p+2) (L loads); compute(p) = 2 kt x 9 MFMA].
__global__ __launch_bounds__(1024, 4) void kb1(const u16* __restrict__ H,
                                               const char* __restrict__ M1b,
                                               const char* __restrict__ M2b,
                                               const float* __restrict__ rs1, const float* __restrict__ rs2,
                                               const float* __restrict__ q1, const float* __restrict__ q2,
                                               const float* __restrict__ Wb, const float* __restrict__ bb,
                                               float* __restrict__ out) {
  __shared__ u16 bt[3][18432];             // 3 x 2-slab B buffers (110.6 KB)
  __shared__ u16 mkb[3][2048];             // 3 x 4KB mask slabs: [m1 kt0][m2 kt0][m1 kt1][m2 kt1]
  __shared__ float f2pf[2][128][16];       // m2@h2 kf-partials (16 KB)
  __shared__ u16 f2s[128 * 40];            // f2 bf16, K padded to 32 (10 KB)
  __shared__ u16 wb2s[4096];               // Wb2 padded to K=32 (8 KB)  -> ~154 KB total

  const int tid = threadIdx.x;
  const int bid = blockIdx.x;
  const int b = bid & 7;
  const int i0 = (bid >> 3) * 128;

  const int w = tid >> 6, l = tid & 63, lr = l & 15, lg = l >> 4;
  const int g = w >> 2, c = w & 3;
  const int fm2 = w & 7, kf2 = w >> 3;
  const int lgsh = lg * 8;

  // B-chunk offsets within a 2-slab phase (u16 units), b folded in
  auto choff = [&](int ch) -> uint32_t {
    int slab = (ch >= 1152) ? 1 : 0;
    int r = ch - slab * 1152;
    return (uint32_t)(slab * 73728 + (r < 576 ? b * 4608 + r * 8 : 36864 + b * 4608 + (r - 576) * 8));
  };
  const u16* pB0 = H + choff(tid);
  const u16* pB1 = H + choff(1024 + tid);
  const u16* pB2 = H + choff(tid < 256 ? 2048 + tid : 2048);   // used only tid<256
  const int dB0 = tid * 16, dB1 = (1024 + tid) * 16, dB2 = (2048 + tid) * 16;
  // mask chunks: tid in [256,512): c = tid-256, region = c>>6 (m1/m2 x kt0/kt1), rowchunk = c&63
  const int mc = tid - 256;
  const char* pM = (((mc >> 6) & 1) ? M2b : M1b) + (size_t)((mc >> 7) & 1) * 32768
                 + (size_t)i0 * 8 + (size_t)(mc & 63) * 16;
  const int dM = mc * 16;

#define STAGE(BUF) { \
    GLOAD16(pB0, (char*)&bt[BUF][0] + dB0); \
    GLOAD16(pB1, (char*)&bt[BUF][0] + dB1); \
    if (tid < 256) GLOAD16(pB2, (char*)&bt[BUF][0] + dB2); \
    else if (tid < 512) GLOAD16(pM, (char*)&mkb[BUF][0] + dM); \
    pB0 += 147456; pB1 += 147456; pB2 += 147456; pM += 65536; }

  // compute-phase LDS fragment offsets (u16, within one slab)
  const int fA0 = (c * 2 + 0) * 512 + l * 8;
  const int fA1 = (c * 2 + 1) * 512 + l * 8;
  const int fB0 = 4608 + fA0;
  const int fB1 = 4608 + fA1;
  const int fM  = kf2 * 4608 + 4096 + l * 8;

  f32x4 zz = {0.f, 0.f, 0.f, 0.f};
  f32x4 acc00 = zz, acc01 = zz, acc10 = zz, acc11 = zz;
  f32x4 acc2 = zz;

#define WAITV { if (w < 8) asm volatile("s_waitcnt vmcnt(3)" ::: "memory"); \
                else asm volatile("s_waitcnt vmcnt(2)" ::: "memory"); }

#define CKT(BUF, S) { \
    const u16* src_ = &bt[BUF][(S) * 9216]; \
    const char* mk_ = (const char*)&mkb[BUF][0] + (S) * 2048; \
    uint2 c0_ = *(const uint2*)(mk_ + ((g * 2 + 0) * 16 + lr) * 8); \
    uint2 c1_ = *(const uint2*)(mk_ + ((g * 2 + 1) * 16 + lr) * 8); \
    uint32_t c2_ = *(const uint32_t*)(mk_ + 1024 + (fm2 * 16 + lr) * 8 + kf2 * 4); \
    short8 bA0_ = *(const short8*)(src_ + fA0); \
    short8 bA1_ = *(const short8*)(src_ + fA1); \
    short8 bB0_ = *(const short8*)(src_ + fB0); \
    short8 bB1_ = *(const short8*)(src_ + fB1); \
    short8 bM_  = *(const short8*)(src_ + fM); \
    short8 e0x_ = expand_byte(c0_.x, lgsh), e0y_ = expand_byte(c0_.y, lgsh); \
    short8 e1x_ = expand_byte(c1_.x, lgsh), e1y_ = expand_byte(c1_.y, lgsh); \
    short8 e2v_ = expand_byte(c2_, lgsh); \
    __builtin_amdgcn_s_setprio(1); \
    acc00 = MFMA(e0x_, bA0_, acc00, 0, 0, 0); \
    acc01 = MFMA(e0x_, bA1_, acc01, 0, 0, 0); \
    acc00 = MFMA(e0y_, bB0_, acc00, 0, 0, 0); \
    acc01 = MFMA(e0y_, bB1_, acc01, 0, 0, 0); \
    acc10 = MFMA(e1x_, bA0_, acc10, 0, 0, 0); \
    acc11 = MFMA(e1x_, bA1_, acc11, 0, 0, 0); \
    acc10 = MFMA(e1y_, bB0_, acc10, 0, 0, 0); \
    acc11 = MFMA(e1y_, bB1_, acc11, 0, 0, 0); \
    acc2  = MFMA(e2v_, bM_, acc2, 0, 0, 0); \
    __builtin_amdgcn_s_setprio(0); }

#define COMPUTE2(BUF) { CKT(BUF, 0) CKT(BUF, 1) }

  // prologue: stage phases 0,1 (kt 0..3)
  STAGE(0);
  STAGE(1);

  // stage Wb2 (overlaps prologue latency)
#pragma unroll
  for (int i = 0; i < 4; ++i) {
    int e = i * 1024 + tid;
    int r_ = e & 7, nn = (e >> 3) & 127, jb = e >> 10;
    int k = jb * 8 + r_;
    wb2s[e] = f2bf((k < 16) ? Wb[(128 + k) * 128 + nn] : 0.f);
  }

  for (int it = 0; it < 10; ++it) {        // phases 0..29 (stage 2..31)
    WAITV; __builtin_amdgcn_s_barrier(); STAGE(2); COMPUTE2(0);
    WAITV; __builtin_amdgcn_s_barrier(); STAGE(0); COMPUTE2(1);
    WAITV; __builtin_amdgcn_s_barrier(); STAGE(1); COMPUTE2(2);
  }
  WAITV; __builtin_amdgcn_s_barrier(); COMPUTE2(0);                            // phase 30
  { asm volatile("s_waitcnt vmcnt(0)" ::: "memory");
    __builtin_amdgcn_s_barrier(); COMPUTE2(1); }                               // phase 31

  // epilogue: combine m2 kf-partials -> f2 bf16 tile
#pragma unroll
  for (int gg = 0; gg < 4; ++gg)
    f2pf[kf2][fm2 * 16 + lg * 4 + gg][lr] = acc2[gg];
  __syncthreads();
#pragma unroll
  for (int j = 0; j < 2; ++j) {
    int e = j * 1024 + tid;                // 128x16 = 2048 elems
    int row = e >> 4, col = e & 15;
    f2s[row * 40 + col] = f2bf(f2pf[0][row][col] + f2pf[1][row][col]);
    f2s[row * 40 + 16 + col] = 0;
  }
  __syncthreads();

  // epilogue MFMA: acc[i][fj] += f2frag(fm=2g+i) x Wb2frag(fn=2c+fj)
  short8 bw0 = *(const short8*)(wb2s + ((lg * 128) + (c * 2 + 0) * 16 + lr) * 8);
  short8 bw1 = *(const short8*)(wb2s + ((lg * 128) + (c * 2 + 1) * 16 + lr) * 8);
  {
    short8 af0 = *(const short8*)(f2s + ((g * 2 + 0) * 16 + lr) * 40 + lg * 8);
    short8 af1 = *(const short8*)(f2s + ((g * 2 + 1) * 16 + lr) * 40 + lg * 8);
    acc00 = MFMA(af0, bw0, acc00, 0, 0, 0);
    acc01 = MFMA(af0, bw1, acc01, 0, 0, 0);
    acc10 = MFMA(af1, bw0, acc10, 0, 0, 0);
    acc11 = MFMA(af1, bw1, acc11, 0, 0, 0);
  }

  // final: + rs1*q1 + rs2*q2 + bb, store f32
  const int col0 = (c * 2 + 0) * 16 + lr, col1 = (c * 2 + 1) * 16 + lr;
  const float q10 = q1[col0], q20 = q2[col0], bb0 = bb[col0];
  const float q11 = q1[col1], q21 = q2[col1], bb1 = bb[col1];
#pragma unroll
  for (int i = 0; i < 2; ++i) {
    f32x4 a0 = i ? acc10 : acc00;
    f32x4 a1 = i ? acc11 : acc01;
#pragma unroll
    for (int gg = 0; gg < 4; ++gg) {
      int row = (g * 2 + i) * 16 + lg * 4 + gg;
      float r1 = rs1[i0 + row], r2 = rs2[i0 + row];
      size_t obase = ((size_t)b * 4096 + i0 + row) * 128;
      out[obase + col0] = a0[gg] + r1 * q10 + r2 * q20 + bb0;
      out[obase + col1] = a1[gg] + r1 * q11 + r2 * q21 + bb1;
    }
  }
}

extern "C" void kernel_launch(void* const* d_in, const int* in_sizes, int n_in,
                              void* d_out, int out_size, void* d_ws, size_t ws_size,
                              hipStream_t stream) {
  const float* x  = (const float*)d_in[0];
  const int*   sp = (const int*)d_in[1];
  const float* W1 = (const float*)d_in[2];
  const float* b1 = (const float*)d_in[3];
  const float* W2 = (const float*)d_in[4];
  const float* b2 = (const float*)d_in[5];
  const float* Wb = (const float*)d_in[6];
  const float* bb = (const float*)d_in[7];
  float* out = (float*)d_out;
  char* ws = (char*)d_ws;

  u16* H = (u16*)(ws + WS_H);
  float* q1 = (float*)(ws + WS_Q1);
  float* q2 = (float*)(ws + WS_Q2);
  unsigned long long* m1p = (unsigned long long*)(ws + WS_M1P);
  unsigned long long* m2p = (unsigned long long*)(ws + WS_M2P);
  float* rs1 = (float*)(ws + WS_RS1);
  float* rs2 = (float*)(ws + WS_RS2);
  u16* wsbg = (u16*)(ws + WS_WSB);

  k0<<<1088, 256, 0, stream>>>(sp, m1p, m2p, rs1, rs2, W1, Wb, b1, b2, W2, q1, q2, wsbg);
  kproj<<<512, 256, 0, stream>>>(x, wsbg, H);
  kb1<<<256, 1024, 0, stream>>>(H, (const char*)m1p, (const char*)m2p,
                                rs1, rs2, q1, q2, Wb, bb, out);
}